// Round 3
// baseline (205.618 us; speedup 1.0000x reference)
//
#include <hip/hip_runtime.h>
#include <hip/hip_bf16.h>
#include <math.h>

// Problem constants
#define B_  64
#define L_  512
#define D_  768
#define K_  6      // NUM_LABELS
#define P_  3      // POL_DIM

#define POOL_BLOCKS 64             // one block per batch (no atomics, no seed)
#define ATE_BLOCKS  4096           // 32768 rows / (4 waves x 2 rows)

typedef float f4_t __attribute__((ext_vector_type(4)));

// select a[i] from a register-resident 6-array without dynamic indexing
__device__ __forceinline__ float sel6(const float a[K_], int i) {
  float r = a[0];
  r = (i == 1) ? a[1] : r;
  r = (i == 2) ? a[2] : r;
  r = (i == 3) ? a[3] : r;
  r = (i == 4) ? a[4] : r;
  r = (i == 5) ? a[5] : r;
  return r;
}

// ---------------------------------------------------------------------------
// Single fused kernel, self-sufficient blocks (no inter-block deps, no ws).
//   blockIdx <  64  : pooler+APC for batch b = blockIdx (overlaps ATE stream)
//   blockIdx >= 64  : ATE role, 8 rows of one batch; wave 0 derives the
//                     compaction map from valid[] via shuffle-scan while
//                     waves 1-3 stage W_cls^T into LDS.
// ---------------------------------------------------------------------------
__global__ __launch_bounds__(256) void k_fused(
    const float* __restrict__ x, const int* __restrict__ valid,
    const float* __restrict__ w_cls, const float* __restrict__ b_cls,
    const float* __restrict__ w_pool, const float* __restrict__ b_pool,
    const float* __restrict__ w_apc, const float* __restrict__ b_apc,
    float* __restrict__ out, float* __restrict__ out_apc) {
  const int wid = threadIdx.x >> 6;
  const int lane = threadIdx.x & 63;

  if (blockIdx.x < POOL_BLOCKS) {
    // ================= pooler + APC head, batch b =================
    __shared__ int sfirst;
    __shared__ float spart[4][P_];
    const int b = blockIdx.x;

    if (wid == 0) {
      // find first valid token: lane i covers tokens 8i..8i+7
      const int4* vp = (const int4*)(valid + b * L_);
      const int4 va = vp[lane * 2];
      const int4 vb = vp[lane * 2 + 1];
      const int v[8] = {va.x, va.y, va.z, va.w, vb.x, vb.y, vb.z, vb.w};
      int loc = 1 << 30;
#pragma unroll
      for (int t = 7; t >= 0; --t)
        if (v[t]) loc = 8 * lane + t;
#pragma unroll
      for (int off = 32; off >= 1; off >>= 1) {
        int o = __shfl_xor(loc, off, 64);
        loc = (o < loc) ? o : loc;
      }
      if (lane == 0) sfirst = (loc < (1 << 30)) ? loc : -1;
    }
    __syncthreads();
    const int src = sfirst;

    // thread t handles j = t, t+256, t+512
    const int t = threadIdx.x;
    float acc0 = 0.f, acc1 = 0.f, acc2 = 0.f;
    if (src >= 0) {
      const f4_t* x4 = (const f4_t*)(x + ((size_t)(b * L_ + src)) * D_);
#pragma unroll 2
      for (int i = 0; i < D_ / 4; ++i) {
        const f4_t xv = x4[i];  // wave-uniform broadcast load
        const float* w = w_pool + (size_t)(4 * i) * D_ + t;
        acc0 += xv.x * w[0] + xv.y * w[D_] + xv.z * w[2 * D_] + xv.w * w[3 * D_];
        acc1 += xv.x * w[256] + xv.y * w[D_ + 256] + xv.z * w[2 * D_ + 256] + xv.w * w[3 * D_ + 256];
        acc2 += xv.x * w[512] + xv.y * w[D_ + 512] + xv.z * w[2 * D_ + 512] + xv.w * w[3 * D_ + 512];
      }
    }
    const float v0 = tanhf(acc0 + b_pool[t]);
    const float v1 = tanhf(acc1 + b_pool[t + 256]);
    const float v2 = tanhf(acc2 + b_pool[t + 512]);

    float p[P_];
#pragma unroll
    for (int c = 0; c < P_; ++c)
      p[c] = v0 * w_apc[t * P_ + c] + v1 * w_apc[(t + 256) * P_ + c] +
             v2 * w_apc[(t + 512) * P_ + c];
#pragma unroll
    for (int off = 32; off >= 1; off >>= 1) {
#pragma unroll
      for (int c = 0; c < P_; ++c) p[c] += __shfl_xor(p[c], off, 64);
    }
    if (lane == 0) {
#pragma unroll
      for (int c = 0; c < P_; ++c) spart[wid][c] = p[c];
    }
    __syncthreads();
    if (threadIdx.x < P_) {
      const int c = threadIdx.x;
      out_apc[b * P_ + c] = spart[0][c] + spart[1][c] + spart[2][c] +
                            spart[3][c] + b_apc[c];
    }
    return;
  }

  // ================= ATE role =================
  __shared__ float swt[K_ * D_];  // 18 KB: W_cls^T [6][768]
  __shared__ int smap[8];         // src token for this block's 8 rows

  const int ab = blockIdx.x - POOL_BLOCKS;
  const int row0b = ab * 8;       // first row of this block
  const int b = row0b >> 9;
  const int jbase = row0b & 511;  // rank of first row within batch

  if (wid == 0) {
    // compaction map: lane i covers tokens 8i..8i+7 of batch b
    const int4* vp = (const int4*)(valid + b * L_);
    const int4 va = vp[lane * 2];
    const int4 vb = vp[lane * 2 + 1];
    const int v[8] = {va.x, va.y, va.z, va.w, vb.x, vb.y, vb.z, vb.w};
    int cnt = 0;
#pragma unroll
    for (int t = 0; t < 8; ++t) cnt += v[t];
    int pre = cnt;  // inclusive -> exclusive below
#pragma unroll
    for (int off = 1; off < 64; off <<= 1) {
      const int n = __shfl_up(pre, off, 64);
      pre += (lane >= off) ? n : 0;
    }
    pre -= cnt;
    if (lane < 8) smap[lane] = -1;
    int run = pre;
#pragma unroll
    for (int t = 0; t < 8; ++t) {
      if (v[t]) {
        const int rel = run - jbase;
        if (rel >= 0 && rel < 8) smap[rel] = 8 * lane + t;
        ++run;
      }
    }
  } else {
    // waves 1-3 (192 threads) stage W_cls^T into LDS, conflict-free banks
    const int u = threadIdx.x - 64;  // 0..191
#pragma unroll
    for (int q = 0; q < 4; ++q) {
      const int d = u + 192 * q;
      const float* wsrc = w_cls + d * K_;
#pragma unroll
      for (int k = 0; k < K_; ++k) swt[k * D_ + d] = wsrc[k];
    }
  }
  __syncthreads();

  const int row0 = row0b + wid * 2;  // 2 consecutive rows, same batch
  const int src0 = smap[wid * 2];
  const int src1 = smap[wid * 2 + 1];

  float a0[K_] = {0.f, 0.f, 0.f, 0.f, 0.f, 0.f};
  float a1[K_] = {0.f, 0.f, 0.f, 0.f, 0.f, 0.f};

  if (src0 >= 0) {
    // invalid rows are a suffix: src1<0 => reload src0's row (L1 hit, discarded)
    const int s1 = (src1 >= 0) ? src1 : src0;
    const f4_t* x0 = (const f4_t*)(x + ((size_t)(b * L_ + src0)) * D_);
    const f4_t* x1 = (const f4_t*)(x + ((size_t)(b * L_ + s1)) * D_);
#pragma unroll
    for (int c = 0; c < 3; ++c) {
      const f4_t xv0 = __builtin_nontemporal_load(&x0[lane + 64 * c]);
      const f4_t xv1 = __builtin_nontemporal_load(&x1[lane + 64 * c]);
      const int d4 = 4 * (lane + 64 * c);
#pragma unroll
      for (int k = 0; k < K_; ++k) {
        const float* w = swt + k * D_ + d4;
        a0[k] += xv0.x * w[0] + xv0.y * w[1] + xv0.z * w[2] + xv0.w * w[3];
        a1[k] += xv1.x * w[0] + xv1.y * w[1] + xv1.z * w[2] + xv1.w * w[3];
      }
    }
#pragma unroll
    for (int k = 0; k < K_; ++k) {
#pragma unroll
      for (int off = 32; off >= 1; off >>= 1) {
        a0[k] += __shfl_xor(a0[k], off, 64);
        a1[k] += __shfl_xor(a1[k], off, 64);
      }
    }
  }

  // rows 2r,2r+1 contiguous: lanes 0..11 store 12 contiguous floats
  if (lane < 12) {
    const int idx = (lane < 6) ? lane : lane - 6;
    float s;
    if (lane < 6) s = (src0 >= 0) ? sel6(a0, idx) : 0.f;
    else          s = (src1 >= 0) ? sel6(a1, idx) : 0.f;
    out[(size_t)row0 * K_ + lane] = s + b_cls[idx];
  }
}

// ---------------------------------------------------------------------------
extern "C" void kernel_launch(void* const* d_in, const int* in_sizes, int n_in,
                              void* d_out, int out_size, void* d_ws, size_t ws_size,
                              hipStream_t stream) {
  const float* x      = (const float*)d_in[0];  // [B,L,D]
  const int*   valid  = (const int*)d_in[1];    // [B,L]
  const float* w_cls  = (const float*)d_in[2];  // [D,K]
  const float* b_cls  = (const float*)d_in[3];  // [K]
  const float* w_pool = (const float*)d_in[4];  // [D,D]
  const float* b_pool = (const float*)d_in[5];  // [D]
  const float* w_apc  = (const float*)d_in[6];  // [D,P]
  const float* b_apc  = (const float*)d_in[7];  // [P]

  float* out     = (float*)d_out;
  float* out_apc = out + (size_t)B_ * L_ * K_;

  k_fused<<<POOL_BLOCKS + ATE_BLOCKS, 256, 0, stream>>>(
      x, valid, w_cls, b_cls, w_pool, b_pool, w_apc, b_apc, out, out_apc);
}

// Round 5
// 203.755 us; speedup vs baseline: 1.0091x; 1.0091x over previous
//
#include <hip/hip_runtime.h>
#include <hip/hip_bf16.h>
#include <math.h>

// Problem constants
#define B_  64
#define L_  512
#define D_  768
#define K_  6      // NUM_LABELS
#define P_  3      // POL_DIM

#define POOL_BLOCKS 64             // one block per batch (no atomics)
#define ATE_BLOCKS  1024           // 16/batch; block = 4 waves x 8 rows = 32 ranks

typedef float f4_t __attribute__((ext_vector_type(4)));

// ---- DPP wave64 sum (result valid in lane 63), VALU pipe only -------------
// ctrl/rowmask must be integer-constant expressions -> template params.
template <int CTRL, int ROWMASK>
__device__ __forceinline__ float dpp_add(float x) {
  int moved = __builtin_amdgcn_update_dpp(0, __float_as_int(x), CTRL, ROWMASK,
                                          0xf, false);
  return x + __int_as_float(moved);
}
__device__ __forceinline__ float wave_sum63(float x) {
  x = dpp_add<0x111, 0xf>(x);  // row_shr:1
  x = dpp_add<0x112, 0xf>(x);  // row_shr:2
  x = dpp_add<0x114, 0xf>(x);  // row_shr:4
  x = dpp_add<0x118, 0xf>(x);  // row_shr:8
  x = dpp_add<0x142, 0xa>(x);  // row_bcast:15 -> rows 1,3
  x = dpp_add<0x143, 0xc>(x);  // row_bcast:31 -> row 3 (and 2's upper halves)
  return x;                    // lane 63 = full 64-lane sum
}

// ---------------------------------------------------------------------------
// Single fused kernel, barrier-free ATE waves.
//   blockIdx <  64  : pooler+APC for batch b = blockIdx
//   blockIdx >= 64  : ATE, 8 compact rows per wave; weights in VGPRs,
//                     DPP reductions, per-wave valid[] scan, bias fast path.
// ---------------------------------------------------------------------------
__global__ __launch_bounds__(256) void k_fused(
    const float* __restrict__ x, const int* __restrict__ valid,
    const float* __restrict__ w_cls, const float* __restrict__ b_cls,
    const float* __restrict__ w_pool, const float* __restrict__ b_pool,
    const float* __restrict__ w_apc, const float* __restrict__ b_apc,
    float* __restrict__ out, float* __restrict__ out_apc) {
  const int wid = threadIdx.x >> 6;
  const int lane = threadIdx.x & 63;

  if (blockIdx.x < POOL_BLOCKS) {
    // ================= pooler + APC head, batch b (unchanged, verified) ====
    __shared__ int sfirst;
    __shared__ float spart[4][P_];
    const int b = blockIdx.x;

    if (wid == 0) {
      const int4* vp = (const int4*)(valid + b * L_);
      const int4 va = vp[lane * 2];
      const int4 vb = vp[lane * 2 + 1];
      const int v[8] = {va.x, va.y, va.z, va.w, vb.x, vb.y, vb.z, vb.w};
      int loc = 1 << 30;
#pragma unroll
      for (int t = 7; t >= 0; --t)
        if (v[t]) loc = 8 * lane + t;
#pragma unroll
      for (int off = 32; off >= 1; off >>= 1) {
        int o = __shfl_xor(loc, off, 64);
        loc = (o < loc) ? o : loc;
      }
      if (lane == 0) sfirst = (loc < (1 << 30)) ? loc : -1;
    }
    __syncthreads();
    const int src = sfirst;

    const int t = threadIdx.x;
    float acc0 = 0.f, acc1 = 0.f, acc2 = 0.f;
    if (src >= 0) {
      const f4_t* x4 = (const f4_t*)(x + ((size_t)(b * L_ + src)) * D_);
#pragma unroll 2
      for (int i = 0; i < D_ / 4; ++i) {
        const f4_t xv = x4[i];  // wave-uniform broadcast load
        const float* w = w_pool + (size_t)(4 * i) * D_ + t;
        acc0 += xv.x * w[0] + xv.y * w[D_] + xv.z * w[2 * D_] + xv.w * w[3 * D_];
        acc1 += xv.x * w[256] + xv.y * w[D_ + 256] + xv.z * w[2 * D_ + 256] + xv.w * w[3 * D_ + 256];
        acc2 += xv.x * w[512] + xv.y * w[D_ + 512] + xv.z * w[2 * D_ + 512] + xv.w * w[3 * D_ + 512];
      }
    }
    const float v0 = tanhf(acc0 + b_pool[t]);
    const float v1 = tanhf(acc1 + b_pool[t + 256]);
    const float v2 = tanhf(acc2 + b_pool[t + 512]);

    float p[P_];
#pragma unroll
    for (int c = 0; c < P_; ++c)
      p[c] = v0 * w_apc[t * P_ + c] + v1 * w_apc[(t + 256) * P_ + c] +
             v2 * w_apc[(t + 512) * P_ + c];
#pragma unroll
    for (int off = 32; off >= 1; off >>= 1) {
#pragma unroll
      for (int c = 0; c < P_; ++c) p[c] += __shfl_xor(p[c], off, 64);
    }
    if (lane == 0) {
#pragma unroll
      for (int c = 0; c < P_; ++c) spart[wid][c] = p[c];
    }
    __syncthreads();
    if (threadIdx.x < P_) {
      const int c = threadIdx.x;
      out_apc[b * P_ + c] = spart[0][c] + spart[1][c] + spart[2][c] +
                            spart[3][c] + b_apc[c];
    }
    return;
  }

  // ================= ATE role (barrier-free waves) =================
  __shared__ int smap[4 * 8];  // 8 ranks per wave

  const int ab = blockIdx.x - POOL_BLOCKS;
  const int b = ab >> 4;                       // 16 blocks per batch
  const int jb = ((ab & 15) << 5) + (wid << 3);  // this wave's first rank

  // ---- per-wave scan of valid[b][:] (once; 2 int4 loads + 6 shfl_up) ----
  const int4* vp = (const int4*)(valid + b * L_);
  const int4 va = vp[lane * 2];
  const int4 vb2 = vp[lane * 2 + 1];
  const int v[8] = {va.x, va.y, va.z, va.w, vb2.x, vb2.y, vb2.z, vb2.w};
  int cnt = 0;
#pragma unroll
  for (int t = 0; t < 8; ++t) cnt += v[t];
  int pre = cnt;
#pragma unroll
  for (int off = 1; off < 64; off <<= 1) {
    const int n = __shfl_up(pre, off, 64);
    pre += (lane >= off) ? n : 0;
  }
  pre -= cnt;                                  // exclusive prefix (tokens < 8*lane)
  const int nvalid = __shfl(pre + cnt, 63);    // total valid in batch

  // bias vectors (wave-uniform): 12 floats = {b0..b5,b0..b5} as 3 float4
  const float bc0 = b_cls[0], bc1 = b_cls[1], bc2 = b_cls[2];
  const float bc3 = b_cls[3], bc4 = b_cls[4], bc5 = b_cls[5];
  const f4_t bias0 = {bc0, bc1, bc2, bc3};
  const f4_t bias1 = {bc4, bc5, bc0, bc1};
  const f4_t bias2 = {bc2, bc3, bc4, bc5};

  float* orow = out + ((size_t)(b * L_ + jb)) * K_;  // 8-row slab (48 floats)

  if (jb >= nvalid) {
    // whole wave invalid: bulk bias fill, 12 f4 stores, done
    if (lane < 12) {
      const int m = lane % 3;
      const f4_t s = (m == 0) ? bias0 : ((m == 1) ? bias1 : bias2);
      ((f4_t*)orow)[lane] = s;
    }
    return;
  }

  // ---- rank -> token map for this wave's 8 ranks (same-wave LDS, no barrier)
  if (lane < 8) smap[wid * 8 + lane] = -1;
  int run = pre;
#pragma unroll
  for (int t = 0; t < 8; ++t) {
    if (v[t]) {
      const int rel = run - jb;
      if ((unsigned)rel < 8u) smap[wid * 8 + rel] = 8 * lane + t;
      ++run;
    }
  }
  const int smap_reg = smap[wid * 8 + (lane & 7)];

  // ---- weights into VGPRs: lane's 24-float W_cls slice per chunk c --------
  // chunk c, lane l covers d = 4*(l + 64c).. +3 -> floats [24l+1536c, +24)
  f4_t wr[3][6];
  const f4_t* w4 = (const f4_t*)w_cls;
#pragma unroll
  for (int c = 0; c < 3; ++c) {
    const f4_t* p = w4 + 384 * c + 6 * lane;
#pragma unroll
    for (int j = 0; j < 6; ++j) wr[c][j] = p[j];
  }

  const float* xb = x + (size_t)b * L_ * D_;

#pragma unroll
  for (int pp = 0; pp < 4; ++pp) {
    const int r0 = jb + 2 * pp;
    const int src0 = __builtin_amdgcn_readlane(smap_reg, 2 * pp);
    const int src1 = __builtin_amdgcn_readlane(smap_reg, 2 * pp + 1);
    f4_t* o = (f4_t*)(out + ((size_t)(b * L_ + r0)) * K_);  // 48B, 16B-aligned

    if (src0 < 0) {
      if (lane == 63) { o[0] = bias0; o[1] = bias1; o[2] = bias2; }
      continue;
    }
    const int s1 = (src1 >= 0) ? src1 : src0;
    const f4_t* x0 = (const f4_t*)(xb + (size_t)src0 * D_);
    const f4_t* x1 = (const f4_t*)(xb + (size_t)s1 * D_);
    f4_t xv0[3], xv1[3];
#pragma unroll
    for (int c = 0; c < 3; ++c) {
      xv0[c] = x0[lane + 64 * c];
      xv1[c] = x1[lane + 64 * c];
    }
    float a0[K_] = {0.f, 0.f, 0.f, 0.f, 0.f, 0.f};
    float a1[K_] = {0.f, 0.f, 0.f, 0.f, 0.f, 0.f};
#pragma unroll
    for (int c = 0; c < 3; ++c) {
#pragma unroll
      for (int i = 0; i < 4; ++i) {
        const float xe0 = xv0[c][i];
        const float xe1 = xv1[c][i];
#pragma unroll
        for (int k = 0; k < K_; ++k) {
          const int e = i * K_ + k;
          const float w = wr[c][e >> 2][e & 3];
          a0[k] += xe0 * w;
          a1[k] += xe1 * w;
        }
      }
    }
    // 12 DPP reductions (VALU pipe); sums valid in lane 63
#pragma unroll
    for (int k = 0; k < K_; ++k) {
      a0[k] = wave_sum63(a0[k]);
      a1[k] = wave_sum63(a1[k]);
    }
    if (lane == 63) {
      const bool ok1 = (src1 >= 0);
      const f4_t o0 = {a0[0] + bc0, a0[1] + bc1, a0[2] + bc2, a0[3] + bc3};
      const f4_t o1 = {a0[4] + bc4, a0[5] + bc5,
                       (ok1 ? a1[0] : 0.f) + bc0, (ok1 ? a1[1] : 0.f) + bc1};
      const f4_t o2 = {(ok1 ? a1[2] : 0.f) + bc2, (ok1 ? a1[3] : 0.f) + bc3,
                       (ok1 ? a1[4] : 0.f) + bc4, (ok1 ? a1[5] : 0.f) + bc5};
      o[0] = o0; o[1] = o1; o[2] = o2;
    }
  }
}

// ---------------------------------------------------------------------------
extern "C" void kernel_launch(void* const* d_in, const int* in_sizes, int n_in,
                              void* d_out, int out_size, void* d_ws, size_t ws_size,
                              hipStream_t stream) {
  const float* x      = (const float*)d_in[0];  // [B,L,D]
  const int*   valid  = (const int*)d_in[1];    // [B,L]
  const float* w_cls  = (const float*)d_in[2];  // [D,K]
  const float* b_cls  = (const float*)d_in[3];  // [K]
  const float* w_pool = (const float*)d_in[4];  // [D,D]
  const float* b_pool = (const float*)d_in[5];  // [D]
  const float* w_apc  = (const float*)d_in[6];  // [D,P]
  const float* b_apc  = (const float*)d_in[7];  // [P]

  float* out     = (float*)d_out;
  float* out_apc = out + (size_t)B_ * L_ * K_;

  k_fused<<<POOL_BLOCKS + ATE_BLOCKS, 256, 0, stream>>>(
      x, valid, w_cls, b_cls, w_pool, b_pool, w_apc, b_apc, out, out_apc);
}

// Round 6
// 199.016 us; speedup vs baseline: 1.0332x; 1.0238x over previous
//
#include <hip/hip_runtime.h>
#include <hip/hip_bf16.h>
#include <math.h>

// Problem constants
#define B_  64
#define L_  512
#define D_  768
#define K_  6      // NUM_LABELS
#define P_  3      // POL_DIM

#define POOL_BLOCKS 64             // one block per batch
#define ATE_BLOCKS  1024           // 16/batch; block = 4 waves x 8 tokens

typedef float f4_t __attribute__((ext_vector_type(4)));

// ---- DPP partial sums (ctrl/mask must be literals -> template params) -----
template <int CTRL, int ROWMASK>
__device__ __forceinline__ float dpp_add(float x) {
  int moved = __builtin_amdgcn_update_dpp(0, __float_as_int(x), CTRL, ROWMASK,
                                          0xf, false);
  return x + __int_as_float(moved);
}
// sum within each 16-lane row; result valid in lane 15 of each row
__device__ __forceinline__ float group_sum15(float x) {
  x = dpp_add<0x111, 0xf>(x);  // row_shr:1
  x = dpp_add<0x112, 0xf>(x);  // row_shr:2
  x = dpp_add<0x114, 0xf>(x);  // row_shr:4
  x = dpp_add<0x118, 0xf>(x);  // row_shr:8
  return x;
}

// ---------------------------------------------------------------------------
// Single fused kernel.
//  blockIdx <  64 : pool role, batch b: pooler (wave-split i, LDS reduce),
//                   APC head, and bias-fill of compact rows [nvalid, 512).
//  blockIdx >= 64 : ATE role: wave streams 8 consecutive TOKENS (branch-free,
//                   fully independent loads), 16-lane group per row, scatter-
//                   stores valid tokens at their compaction rank.
// ---------------------------------------------------------------------------
__global__ __launch_bounds__(256) void k_fused(
    const float* __restrict__ x, const int* __restrict__ valid,
    const float* __restrict__ w_cls, const float* __restrict__ b_cls,
    const float* __restrict__ w_pool, const float* __restrict__ b_pool,
    const float* __restrict__ w_apc, const float* __restrict__ b_apc,
    float* __restrict__ out, float* __restrict__ out_apc) {
  const int wid = threadIdx.x >> 6;
  const int lane = threadIdx.x & 63;

  if (blockIdx.x < POOL_BLOCKS) {
    // ================= pool role, batch b =================
    __shared__ f4_t spart[4][192];   // 12 KB partial pooled sums
    __shared__ float sred[4][P_];
    __shared__ int s_first, s_nvalid;
    const int b = blockIdx.x;

    if (wid == 0) {
      // full scan of valid[b][:]: lane covers tokens 8*lane..8*lane+7
      const int4* vp = (const int4*)(valid + b * L_);
      const int4 va = vp[lane * 2];
      const int4 vb = vp[lane * 2 + 1];
      const int m8 = va.x | (va.y << 1) | (va.z << 2) | (va.w << 3) |
                     (vb.x << 4) | (vb.y << 5) | (vb.z << 6) | (vb.w << 7);
      const int cnt = __popc(m8);
      int inc = cnt;
#pragma unroll
      for (int off = 1; off < 64; off <<= 1) {
        const int n = __shfl_up(inc, off, 64);
        inc += (lane >= off) ? n : 0;
      }
      if (lane == 63) s_nvalid = inc;
      int loc = m8 ? (8 * lane + __ffs(m8) - 1) : (1 << 30);
#pragma unroll
      for (int off = 32; off >= 1; off >>= 1) {
        const int o = __shfl_xor(loc, off, 64);
        loc = (o < loc) ? o : loc;
      }
      if (lane == 0) s_first = (loc < (1 << 30)) ? loc : -1;
    }
    __syncthreads();
    const int src = s_first;
    const int nv = s_nvalid;

    // pooled partials: wave w owns i in [192w, 192w+192); lane owns f4 col
    // groups j4 = lane, lane+64, lane+128.  All loads independent f4s.
    f4_t acc0 = {0.f, 0.f, 0.f, 0.f}, acc1 = acc0, acc2 = acc0;
    if (src >= 0) {
      const float* xr = x + ((size_t)(b * L_ + src)) * D_ + wid * 192;
      const f4_t* wp = (const f4_t*)w_pool + (size_t)(wid * 192) * 192;
#pragma unroll 4
      for (int i = 0; i < 192; ++i) {
        const float xs = xr[i];                 // wave-uniform broadcast
        const f4_t* row = wp + (size_t)i * 192;
        acc0 += xs * row[lane];
        acc1 += xs * row[lane + 64];
        acc2 += xs * row[lane + 128];
      }
    }
    spart[wid][lane] = acc0;
    spart[wid][lane + 64] = acc1;
    spart[wid][lane + 128] = acc2;
    __syncthreads();

    // tanh + APC partials: threads 0..191 (waves 0..2 fully active)
    if (threadIdx.x < 192) {
      const int t = threadIdx.x;
      f4_t s = spart[0][t] + spart[1][t] + spart[2][t] + spart[3][t];
      const f4_t bp = ((const f4_t*)b_pool)[t];
      float val[4];
#pragma unroll
      for (int e = 0; e < 4; ++e) val[e] = tanhf(s[e] + bp[e]);
      float p[P_];
#pragma unroll
      for (int c = 0; c < P_; ++c) {
        p[c] = val[0] * w_apc[(4 * t + 0) * P_ + c] +
               val[1] * w_apc[(4 * t + 1) * P_ + c] +
               val[2] * w_apc[(4 * t + 2) * P_ + c] +
               val[3] * w_apc[(4 * t + 3) * P_ + c];
      }
#pragma unroll
      for (int off = 32; off >= 1; off >>= 1) {
#pragma unroll
        for (int c = 0; c < P_; ++c) p[c] += __shfl_xor(p[c], off, 64);
      }
      if (lane == 0) {
#pragma unroll
        for (int c = 0; c < P_; ++c) sred[wid][c] = p[c];
      }
    }
    __syncthreads();
    if (threadIdx.x < P_) {
      const int c = threadIdx.x;
      out_apc[b * P_ + c] = sred[0][c] + sred[1][c] + sred[2][c] + b_apc[c];
    }

    // bias-fill compact rows [nv, 512): float2 pattern {b0b1,b2b3,b4b5}
    const float2 q0 = make_float2(b_cls[0], b_cls[1]);
    const float2 q1 = make_float2(b_cls[2], b_cls[3]);
    const float2 q2 = make_float2(b_cls[4], b_cls[5]);
    float2* ob = (float2*)(out + (size_t)b * L_ * K_);
    for (int f = nv * 3 + threadIdx.x; f < L_ * 3; f += 256) {
      const int m = f % 3;
      ob[f] = (m == 0) ? q0 : ((m == 1) ? q1 : q2);
    }
    return;
  }

  // ================= ATE role: stream 8 consecutive tokens =================
  const int ab = blockIdx.x - POOL_BLOCKS;
  const int b = ab >> 4;                          // 16 blocks per batch
  const int t0 = ((ab & 15) << 5) + (wid << 3);   // first token (multiple of 8)

  // per-wave scan (no load depends on it; compiler overlaps with x loads)
  const int4* vp = (const int4*)(valid + b * L_);
  const int4 va = vp[lane * 2];
  const int4 vb = vp[lane * 2 + 1];
  const int m8 = va.x | (va.y << 1) | (va.z << 2) | (va.w << 3) |
                 (vb.x << 4) | (vb.y << 5) | (vb.z << 6) | (vb.w << 7);
  const int cnt = __popc(m8);
  int pre = cnt;
#pragma unroll
  for (int off = 1; off < 64; off <<= 1) {
    const int n = __shfl_up(pre, off, 64);
    pre += (lane >= off) ? n : 0;
  }
  pre -= cnt;                                     // exclusive prefix
  const int chunk = t0 >> 3;                      // this wave's 8-token chunk
  const int base = __builtin_amdgcn_readlane(pre, chunk);
  const int mask8 = __builtin_amdgcn_readlane(m8, chunk);

  const float bc0 = b_cls[0], bc1 = b_cls[1], bc2 = b_cls[2];
  const float bc3 = b_cls[3], bc4 = b_cls[4], bc5 = b_cls[5];

  const int g = lane >> 4;                        // row group 0..3
  const int s = lane & 15;                        // position within group
  const f4_t* x4 = (const f4_t*)x + ((size_t)(b * L_ + t0)) * (D_ / 4);
  const f4_t* w4 = (const f4_t*)w_cls;
  float* outb = out + (size_t)b * L_ * K_;

#pragma unroll
  for (int h = 0; h < 2; ++h) {
    // group g computes token t0 + 4h + g; lane covers d = 4s + 64c
    const f4_t* xrow = x4 + (size_t)(4 * h + g) * (D_ / 4);
    float a[K_] = {0.f, 0.f, 0.f, 0.f, 0.f, 0.f};
#pragma unroll
    for (int c = 0; c < 12; ++c) {
      const f4_t xv = xrow[s + 16 * c];           // independent across c
      const f4_t* wp = w4 + 96 * c + 6 * s;       // L1-hot (18 KB total)
      f4_t wv[6];
#pragma unroll
      for (int j = 0; j < 6; ++j) wv[j] = wp[j];
#pragma unroll
      for (int i = 0; i < 4; ++i) {
#pragma unroll
        for (int k = 0; k < K_; ++k) {
          const int e = i * K_ + k;
          a[k] += xv[i] * wv[e >> 2][e & 3];
        }
      }
    }
#pragma unroll
    for (int k = 0; k < K_; ++k) a[k] = group_sum15(a[k]);

    const int roff = 4 * h + g;                   // token offset in chunk
    const int bit = (mask8 >> roff) & 1;
    const int rank = base + __popc(mask8 & ((1 << roff) - 1));
    if (s == 15 && bit) {                         // 4 lanes store their rows
      float2* o = (float2*)(outb + (size_t)rank * K_);
      o[0] = make_float2(a[0] + bc0, a[1] + bc1);
      o[1] = make_float2(a[2] + bc2, a[3] + bc3);
      o[2] = make_float2(a[4] + bc4, a[5] + bc5);
    }
  }
}

// ---------------------------------------------------------------------------
extern "C" void kernel_launch(void* const* d_in, const int* in_sizes, int n_in,
                              void* d_out, int out_size, void* d_ws, size_t ws_size,
                              hipStream_t stream) {
  const float* x      = (const float*)d_in[0];  // [B,L,D]
  const int*   valid  = (const int*)d_in[1];    // [B,L]
  const float* w_cls  = (const float*)d_in[2];  // [D,K]
  const float* b_cls  = (const float*)d_in[3];  // [K]
  const float* w_pool = (const float*)d_in[4];  // [D,D]
  const float* b_pool = (const float*)d_in[5];  // [D]
  const float* w_apc  = (const float*)d_in[6];  // [D,P]
  const float* b_apc  = (const float*)d_in[7];  // [P]

  float* out     = (float*)d_out;
  float* out_apc = out + (size_t)B_ * L_ * K_;

  k_fused<<<POOL_BLOCKS + ATE_BLOCKS, 256, 0, stream>>>(
      x, valid, w_cls, b_cls, w_pool, b_pool, w_apc, b_apc, out, out_apc);
}

// Round 7
// 171.491 us; speedup vs baseline: 1.1990x; 1.1605x over previous
//
#include <hip/hip_runtime.h>
#include <hip/hip_bf16.h>
#include <math.h>

// Problem constants
#define B_  64
#define L_  512
#define D_  768
#define K_  6      // NUM_LABELS
#define P_  3      // POL_DIM

#define POOL_BLOCKS 192            // 16 b-groups x 12 j-groups (R2 split)
#define ATE_BLOCKS  1024           // 16/batch; block = 4 waves x 8 ranks

typedef float f4_t __attribute__((ext_vector_type(4)));

// ---- DPP wave64 sum (result valid in lane 63), VALU pipe only -------------
template <int CTRL, int ROWMASK>
__device__ __forceinline__ float dpp_add(float x) {
  int moved = __builtin_amdgcn_update_dpp(0, __float_as_int(x), CTRL, ROWMASK,
                                          0xf, false);
  return x + __int_as_float(moved);
}
__device__ __forceinline__ float wave_sum63(float x) {
  x = dpp_add<0x111, 0xf>(x);  // row_shr:1
  x = dpp_add<0x112, 0xf>(x);  // row_shr:2
  x = dpp_add<0x114, 0xf>(x);  // row_shr:4
  x = dpp_add<0x118, 0xf>(x);  // row_shr:8
  x = dpp_add<0x142, 0xa>(x);  // row_bcast:15
  x = dpp_add<0x143, 0xc>(x);  // row_bcast:31
  return x;                    // lane 63 = full 64-lane sum
}

// ---------------------------------------------------------------------------
// D1: fused kernel.
//  blockIdx < 192 : pool role (R2 split): wave = (batch b, 64-j slice).
//                   Per-lane W column reads (coalesced), wave-uniform x reads,
//                   APC partial -> ws[jg][b][3].  786 KB W traffic per block.
//  blockIdx >=192 : ATE role (R5): 8 compact rows/wave, weights in VGPRs,
//                   DPP reductions, per-wave valid[] scan, bias fast path.
// ---------------------------------------------------------------------------
__global__ __launch_bounds__(256) void k_fused(
    const float* __restrict__ x, const int* __restrict__ valid,
    const float* __restrict__ w_cls, const float* __restrict__ b_cls,
    const float* __restrict__ w_pool, const float* __restrict__ b_pool,
    const float* __restrict__ w_apc, float* __restrict__ out,
    float* __restrict__ ws_apc) {
  const int wid = threadIdx.x >> 6;
  const int lane = threadIdx.x & 63;

  if (blockIdx.x < POOL_BLOCKS) {
    // ================= pool role: batch b, j-slice jg =================
    const int b = (blockIdx.x & 15) * 4 + wid;
    const int jg = blockIdx.x >> 4;          // 0..11
    const int j = jg * 64 + lane;

    // first-valid token via lane-parallel min (2 int4 loads + 6-step butterfly)
    const int4* vp = (const int4*)(valid + b * L_);
    const int4 va = vp[lane * 2];
    const int4 vb = vp[lane * 2 + 1];
    const int m8 = va.x | (va.y << 1) | (va.z << 2) | (va.w << 3) |
                   (vb.x << 4) | (vb.y << 5) | (vb.z << 6) | (vb.w << 7);
    int loc = m8 ? (8 * lane + __ffs(m8) - 1) : (1 << 30);
#pragma unroll
    for (int off = 32; off >= 1; off >>= 1) {
      const int o = __shfl_xor(loc, off, 64);
      loc = (o < loc) ? o : loc;
    }
    const int src = __builtin_amdgcn_readfirstlane(loc);

    float a0 = 0.f, a1 = 0.f, a2 = 0.f, a3 = 0.f;
    if (src < L_) {
      const float* xr = x + ((size_t)(b * L_ + src)) * D_;  // uniform base
      const float* wp = w_pool + j;                          // lane-coalesced
#pragma unroll 4
      for (int i = 0; i < D_; i += 4) {
        a0 += xr[i]     * wp[(size_t)i * D_];
        a1 += xr[i + 1] * wp[(size_t)(i + 1) * D_];
        a2 += xr[i + 2] * wp[(size_t)(i + 2) * D_];
        a3 += xr[i + 3] * wp[(size_t)(i + 3) * D_];
      }
    }
    const float val = tanhf((a0 + a1) + (a2 + a3) + b_pool[j]);

    float p0 = val * w_apc[j * P_ + 0];
    float p1 = val * w_apc[j * P_ + 1];
    float p2 = val * w_apc[j * P_ + 2];
    p0 = wave_sum63(p0);
    p1 = wave_sum63(p1);
    p2 = wave_sum63(p2);
    if (lane == 63) {
      float* d = ws_apc + (jg * B_ + b) * P_;
      d[0] = p0; d[1] = p1; d[2] = p2;
    }
    return;
  }

  // ================= ATE role (R5: barrier-free waves) =================
  __shared__ int smap[4 * 8];  // 8 ranks per wave

  const int ab = blockIdx.x - POOL_BLOCKS;
  const int b = ab >> 4;                         // 16 blocks per batch
  const int jb = ((ab & 15) << 5) + (wid << 3);  // this wave's first rank

  // per-wave scan of valid[b][:]
  const int4* vp = (const int4*)(valid + b * L_);
  const int4 va = vp[lane * 2];
  const int4 vb2 = vp[lane * 2 + 1];
  const int v[8] = {va.x, va.y, va.z, va.w, vb2.x, vb2.y, vb2.z, vb2.w};
  int cnt = 0;
#pragma unroll
  for (int t = 0; t < 8; ++t) cnt += v[t];
  int pre = cnt;
#pragma unroll
  for (int off = 1; off < 64; off <<= 1) {
    const int n = __shfl_up(pre, off, 64);
    pre += (lane >= off) ? n : 0;
  }
  pre -= cnt;                                  // exclusive prefix
  const int nvalid = __shfl(pre + cnt, 63);

  const float bc0 = b_cls[0], bc1 = b_cls[1], bc2 = b_cls[2];
  const float bc3 = b_cls[3], bc4 = b_cls[4], bc5 = b_cls[5];
  const f4_t bias0 = {bc0, bc1, bc2, bc3};
  const f4_t bias1 = {bc4, bc5, bc0, bc1};
  const f4_t bias2 = {bc2, bc3, bc4, bc5};

  float* orow = out + ((size_t)(b * L_ + jb)) * K_;  // 8-row slab

  if (jb >= nvalid) {
    if (lane < 12) {
      const int m = lane % 3;
      const f4_t s = (m == 0) ? bias0 : ((m == 1) ? bias1 : bias2);
      ((f4_t*)orow)[lane] = s;
    }
    return;
  }

  // rank -> token map for this wave's 8 ranks (same-wave LDS, no barrier)
  if (lane < 8) smap[wid * 8 + lane] = -1;
  int run = pre;
#pragma unroll
  for (int t = 0; t < 8; ++t) {
    if (v[t]) {
      const int rel = run - jb;
      if ((unsigned)rel < 8u) smap[wid * 8 + rel] = 8 * lane + t;
      ++run;
    }
  }
  const int smap_reg = smap[wid * 8 + (lane & 7)];

  // weights into VGPRs: lane's 24-float W_cls slice per chunk c
  f4_t wr[3][6];
  const f4_t* w4 = (const f4_t*)w_cls;
#pragma unroll
  for (int c = 0; c < 3; ++c) {
    const f4_t* p = w4 + 384 * c + 6 * lane;
#pragma unroll
    for (int jx = 0; jx < 6; ++jx) wr[c][jx] = p[jx];
  }

  const float* xb = x + (size_t)b * L_ * D_;

#pragma unroll
  for (int pp = 0; pp < 4; ++pp) {
    const int r0 = jb + 2 * pp;
    const int src0 = __builtin_amdgcn_readlane(smap_reg, 2 * pp);
    const int src1 = __builtin_amdgcn_readlane(smap_reg, 2 * pp + 1);
    f4_t* o = (f4_t*)(out + ((size_t)(b * L_ + r0)) * K_);

    if (src0 < 0) {
      if (lane == 63) { o[0] = bias0; o[1] = bias1; o[2] = bias2; }
      continue;
    }
    const int s1 = (src1 >= 0) ? src1 : src0;
    const f4_t* x0 = (const f4_t*)(xb + (size_t)src0 * D_);
    const f4_t* x1 = (const f4_t*)(xb + (size_t)s1 * D_);
    f4_t xv0[3], xv1[3];
#pragma unroll
    for (int c = 0; c < 3; ++c) {
      xv0[c] = x0[lane + 64 * c];
      xv1[c] = x1[lane + 64 * c];
    }
    float a0[K_] = {0.f, 0.f, 0.f, 0.f, 0.f, 0.f};
    float a1[K_] = {0.f, 0.f, 0.f, 0.f, 0.f, 0.f};
#pragma unroll
    for (int c = 0; c < 3; ++c) {
#pragma unroll
      for (int i = 0; i < 4; ++i) {
        const float xe0 = xv0[c][i];
        const float xe1 = xv1[c][i];
#pragma unroll
        for (int k = 0; k < K_; ++k) {
          const int e = i * K_ + k;
          const float w = wr[c][e >> 2][e & 3];
          a0[k] += xe0 * w;
          a1[k] += xe1 * w;
        }
      }
    }
#pragma unroll
    for (int k = 0; k < K_; ++k) {
      a0[k] = wave_sum63(a0[k]);
      a1[k] = wave_sum63(a1[k]);
    }
    if (lane == 63) {
      const bool ok1 = (src1 >= 0);
      const f4_t o0 = {a0[0] + bc0, a0[1] + bc1, a0[2] + bc2, a0[3] + bc3};
      const f4_t o1 = {a0[4] + bc4, a0[5] + bc5,
                       (ok1 ? a1[0] : 0.f) + bc0, (ok1 ? a1[1] : 0.f) + bc1};
      const f4_t o2 = {(ok1 ? a1[2] : 0.f) + bc2, (ok1 ? a1[3] : 0.f) + bc3,
                       (ok1 ? a1[4] : 0.f) + bc4, (ok1 ? a1[5] : 0.f) + bc5};
      o[0] = o0; o[1] = o1; o[2] = o2;
    }
  }
}

// ---------------------------------------------------------------------------
// D2: APC finalize — sum 12 j-group partials per (b,c), add bias.
// ---------------------------------------------------------------------------
__global__ __launch_bounds__(192) void k_apc(
    const float* __restrict__ ws_apc, const float* __restrict__ b_apc,
    float* __restrict__ out_apc) {
  const int t = threadIdx.x;  // 0..191 -> (b, c)
  float s = 0.f;
#pragma unroll
  for (int g = 0; g < 12; ++g) s += ws_apc[g * (B_ * P_) + t];
  out_apc[t] = s + b_apc[t % P_];
}

// ---------------------------------------------------------------------------
extern "C" void kernel_launch(void* const* d_in, const int* in_sizes, int n_in,
                              void* d_out, int out_size, void* d_ws, size_t ws_size,
                              hipStream_t stream) {
  const float* x      = (const float*)d_in[0];  // [B,L,D]
  const int*   valid  = (const int*)d_in[1];    // [B,L]
  const float* w_cls  = (const float*)d_in[2];  // [D,K]
  const float* b_cls  = (const float*)d_in[3];  // [K]
  const float* w_pool = (const float*)d_in[4];  // [D,D]
  const float* b_pool = (const float*)d_in[5];  // [D]
  const float* w_apc  = (const float*)d_in[6];  // [D,P]
  const float* b_apc  = (const float*)d_in[7];  // [P]

  float* out     = (float*)d_out;
  float* out_apc = out + (size_t)B_ * L_ * K_;
  float* ws_apc  = (float*)d_ws;                // 12*64*3 floats = 9216 B

  k_fused<<<POOL_BLOCKS + ATE_BLOCKS, 256, 0, stream>>>(
      x, valid, w_cls, b_cls, w_pool, b_pool, w_apc, out, ws_apc);
  k_apc<<<1, 192, 0, stream>>>(ws_apc, b_apc, out_apc);
}